// Round 1
// baseline (6682.675 us; speedup 1.0000x reference)
//
#include <hip/hip_runtime.h>
#include <hip/hip_bf16.h>
#include <stdint.h>

// LSTM decoder: H=1024, B=4096, T=128, IN=1.
// R13 = R12 numerics (rank-1 pred fold, bf16 h/c, XOR-swizzled LDS) with the
// GEMM core restructured from the m97 2-barrier loop (~823 TF ceiling) to a
// 256x256-tile, 4-phase counted-vmcnt pipeline (T2+T3+T4+T5):
//  - 512 threads = 8 waves (2M x 4N), BK=64, double-buffered 128 KiB LDS
//  - per phase: ds_read subtile || stage 1 half-tile of tile t+1 (2x
//    global_load_lds w16) -> s_waitcnt vmcnt(2) -> raw s_barrier ->
//    setprio(1) + 16 MFMA + setprio(0) -> barrier.  vmcnt never drains to 0
//    inside the loop (only prologue + last tile's first phase).
//  - stage order A-lo,A-hi,B-lo,B-hi; consume quadrant (qm,qn)=(p>>1,p&1):
//    every half-tile is >=2 vmcnt(2)+barrier events old at first ds_read.
//  - B fragments live in registers across phases (24 ds_read_b128/tile/wave).
//  - grid 256 (1 block/CU), bijective XCD swizzle: XCD owns a 4nb x 8mb chunk.

#define HH 1024
#define BB 4096
#define TT 128

#define BM 256            // batch rows per block
#define BN 256            // weight rows per block = 4 gates x 64 j
#define BKK 64            // K tile
#define NT (HH / BKK)     // 16 K-tiles

typedef __bf16 bf16;
typedef __bf16 v8bf __attribute__((ext_vector_type(8)));
typedef float f32x4 __attribute__((ext_vector_type(4)));

__device__ __forceinline__ float fast_sigmoid(float x) {
    return 1.0f / (1.0f + __expf(-x));
}
__device__ __forceinline__ float fast_tanh(float x) {
    return 1.0f - 2.0f / (__expf(2.0f * x) + 1.0f);
}

__device__ __forceinline__ void gload_lds16(const void* g, void* l) {
    __builtin_amdgcn_global_load_lds(
        (const __attribute__((address_space(1))) uint32_t*)(uintptr_t)g,
        (__attribute__((address_space(3))) uint32_t*)(uint32_t)(uintptr_t)l,
        16, 0, 0);
}

#define FENCE() asm volatile("" ::: "memory")
#define BAR() do { FENCE(); __builtin_amdgcn_s_barrier(); FENCE(); } while (0)
#define WAITV2() asm volatile("s_waitcnt vmcnt(2)" ::: "memory")
#define WAITV0() asm volatile("s_waitcnt vmcnt(0)" ::: "memory")

// ---- Prologue kernels ------------------------------------------------------

// Wr row layout: nb*256 + g*64 + jj  <->  Whh row g*HH + nb*64 + jj
// Wr0 = pure Whh (for t=0); Wr1 = Whh + Wih (x) Wout (for t>=1).
__global__ void prep_weights(const float* __restrict__ Whh,
                             const float* __restrict__ bih,
                             const float* __restrict__ bhh,
                             const float* __restrict__ Wih,
                             const float* __restrict__ Wout,
                             const float* __restrict__ bout,
                             bf16* __restrict__ Wr0, bf16* __restrict__ Wr1,
                             float* __restrict__ bias0, float* __restrict__ bias1) {
    int idx = blockIdx.x * blockDim.x + threadIdx.x;
    if (idx < 4 * HH * HH) {
        int k   = idx & (HH - 1);
        int row = idx >> 10;
        int nb  = row >> 8;
        int g   = (row >> 6) & 3;
        int jj  = row & 63;
        int srow = g * HH + nb * 64 + jj;
        float wv = Whh[srow * HH + k];
        Wr0[idx] = (bf16)wv;
        Wr1[idx] = (bf16)(wv + Wih[srow] * Wout[k]);
    }
    if (idx < 4 * HH) {
        float b = bih[idx] + bhh[idx];
        bias0[idx] = b;
        bias1[idx] = b + Wih[idx] * bout[0];
    }
}

__global__ void prep_h(const float* __restrict__ h0, bf16* __restrict__ hb) {
    int idx = blockIdx.x * blockDim.x + threadIdx.x;
    if (idx < BB * HH) hb[idx] = (bf16)h0[idx];
}

__global__ void prep_c(const float* __restrict__ c0, bf16* __restrict__ cb) {
    int idx = blockIdx.x * blockDim.x + threadIdx.x;
    if (idx < BB * HH) cb[idx] = (bf16)c0[idx];
}

// all pred slots = b_out; atomics add the raw dot on top
__global__ void prep_pred(float* __restrict__ predbuf, const float* __restrict__ b_out) {
    int idx = blockIdx.x * blockDim.x + threadIdx.x;
    if (idx < (TT + 1) * BB) predbuf[idx] = b_out[0];
}

// ---- Per-step fused GEMM + cell update ------------------------------------
// 256 blocks = 16 nb x 16 mb. Block tile: 256 batch x 256 weight rows.
// Wave (waveM, waveN): 128 batch x (4 gates x 16 j); acc[mi][g].

__global__ __launch_bounds__(512, 2)
void lstm_step(const bf16* __restrict__ hread, bf16* __restrict__ hwrite,
               bf16* __restrict__ cbuf,
               const bf16* __restrict__ Wr, const float* __restrict__ biasp,
               const float* __restrict__ Wout, float* __restrict__ predbuf_w) {
    // unpadded 128-B rows, XOR-swizzled: phys 16B-chunk = logical ^ (row&7)
    __shared__ __align__(16) bf16 As[2][BM][BKK];   // h tiles:  2 x 256 x 64 (64 KB)
    __shared__ __align__(16) bf16 Bs[2][BN][BKK];   // weights:  2 x 256 x 64 (64 KB)

    const int tid   = threadIdx.x;
    const int lane  = tid & 63;
    const int w     = tid >> 6;        // 0..7
    const int waveM = w >> 2;          // 0..1 : batch half
    const int waveN = w & 3;           // 0..3 : j quarter
    const int quad  = lane >> 4, l15 = lane & 15;
    const int swr   = l15 & 7;         // read-side swizzle key (row & 7)

    // bijective XCD swizzle: XCD x owns nb in [(x&3)*4,+4), mb in [(x>>2)*8,+8)
    const int bid = blockIdx.x;
    const int xcd = bid & 7, loc = bid >> 3;
    const int nb  = (xcd & 3) * 4 + (loc & 3);     // 0..15 weight block
    const int mb  = (xcd >> 2) * 8 + (loc >> 2);   // 0..15 batch block
    const int blockB = mb * BM;

    const bf16* Asrc = hread + (size_t)blockB * HH;
    const bf16* Bsrc = Wr + (size_t)nb * BN * HH;

    const int r8  = lane >> 3;              // 0..7 row within 8-row stage group
    const int gc8 = ((lane & 7) ^ r8) * 8;  // pre-swizzled global chunk (elems)

    // epilogue constants; bias folded into acc init
    const int j = nb * 64 + waveN * 16 + l15;
    const float wo = Wout[j];

    f32x4 acc[8][4];  // [m-frag][gate], bias-initialized
#pragma unroll
    for (int g = 0; g < 4; g++) {
        const float bv = biasp[g * HH + j];
#pragma unroll
        for (int mi = 0; mi < 8; mi++)
            acc[mi][g] = (f32x4){bv, bv, bv, bv};
    }

    // ---- prologue: stage K-tile 0 into buffer 0, one-time full drain ----
#pragma unroll
    for (int h2 = 0; h2 < 2; h2++)
#pragma unroll
        for (int c = 0; c < 2; c++) {
            const int rowb = h2 * 128 + w * 16 + c * 8;
            gload_lds16(Asrc + (size_t)(rowb + r8) * HH + gc8, &As[0][rowb][0]);
            gload_lds16(Bsrc + (size_t)(rowb + r8) * HH + gc8, &Bs[0][rowb][0]);
        }
    WAITV0();
    BAR();

    // ---- main loop: 16 K-tiles x 4 phases ----
    for (int t = 0; t < NT; t++) {
        const int buf = t & 1, nxt = buf ^ 1;
        const int kn = (t + 1) * BKK;       // next tile's K offset (elems)
        const bool dost = (t < NT - 1);
        v8bf a[4][2], b[4][2];
#pragma unroll
        for (int p = 0; p < 4; p++) {
            // --- ds_read register subtiles for this phase ---
            if (p == 0 || p == 2) {         // A fragments for qm = p>>1
                const int qm = p >> 1;
#pragma unroll
                for (int mi = 0; mi < 4; mi++)
#pragma unroll
                    for (int kk = 0; kk < 2; kk++)
                        a[mi][kk] = *(const v8bf*)
                            &As[buf][waveM * 128 + qm * 64 + mi * 16 + l15]
                                [((kk * 4 + quad) ^ swr) * 8];
            }
            if (p <= 1) {                   // B fragments: gates 2p, 2p+1
#pragma unroll
                for (int g2 = 0; g2 < 2; g2++)
#pragma unroll
                    for (int kk = 0; kk < 2; kk++)
                        b[p * 2 + g2][kk] = *(const v8bf*)
                            &Bs[buf][(p * 2 + g2) * 64 + waveN * 16 + l15]
                                [((kk * 4 + quad) ^ swr) * 8];
            }
            // --- stage half-tile p of tile t+1 (2 loads/thread) ---
            if (dost) {
                if (p <= 1) {               // A halves
#pragma unroll
                    for (int c = 0; c < 2; c++) {
                        const int rowb = p * 128 + w * 16 + c * 8;
                        gload_lds16(Asrc + (size_t)(rowb + r8) * HH + kn + gc8,
                                    &As[nxt][rowb][0]);
                    }
                } else {                    // B halves
#pragma unroll
                    for (int c = 0; c < 2; c++) {
                        const int rowb = (p - 2) * 128 + w * 16 + c * 8;
                        gload_lds16(Bsrc + (size_t)(rowb + r8) * HH + kn + gc8,
                                    &Bs[nxt][rowb][0]);
                    }
                }
            }
            // --- counted wait; last tile's first phase drains the pipe ---
            if (p == 0 && !dost) { WAITV0(); } else { WAITV2(); }
            BAR();
            __builtin_amdgcn_s_setprio(1);
            {
                const int qm = p >> 1, qn = p & 1;
#pragma unroll
                for (int mi = 0; mi < 4; mi++)
#pragma unroll
                    for (int g2 = 0; g2 < 2; g2++)
#pragma unroll
                        for (int kk = 0; kk < 2; kk++)
                            acc[qm * 4 + mi][qn * 2 + g2] =
                                __builtin_amdgcn_mfma_f32_16x16x32_bf16(
                                    a[mi][kk], b[qn * 2 + g2][kk],
                                    acc[qm * 4 + mi][qn * 2 + g2], 0, 0, 0);
            }
            __builtin_amdgcn_s_setprio(0);
            BAR();
        }
    }

    // ---- Epilogue: acc[mi][g][r] = gate g (bias incl.) at (batch, j):
    //   batch = blockB + waveM*128 + mi*16 + quad*4 + r
    //   j     = nb*64 + waveN*16 + l15
#pragma unroll
    for (int mi = 0; mi < 8; mi++) {
#pragma unroll
        for (int r = 0; r < 4; r++) {
            const int bq = blockB + waveM * 128 + mi * 16 + quad * 4 + r;
            const float gi = acc[mi][0][r];
            const float gf = acc[mi][1][r];
            const float gg = acc[mi][2][r];
            const float go = acc[mi][3][r];
            const float cprev = (float)cbuf[(size_t)bq * HH + j];
            const float cn = fast_sigmoid(gf) * cprev
                           + fast_sigmoid(gi) * fast_tanh(gg);
            cbuf[(size_t)bq * HH + j] = (bf16)cn;   // in-place, 1 owner/elem
            const float hn = fast_sigmoid(go) * fast_tanh(cn);
            hwrite[(size_t)bq * HH + j] = (bf16)hn;
            float pacc = hn * wo;
            pacc += __shfl_xor(pacc, 1);
            pacc += __shfl_xor(pacc, 2);
            pacc += __shfl_xor(pacc, 4);
            pacc += __shfl_xor(pacc, 8);
            if (l15 == 0) atomicAdd(&predbuf_w[bq], pacc);
        }
    }
}

// ---- Output transpose: out[b][t] = pred_t[b] ------------------------------

__global__ void write_out(const float* __restrict__ predbuf, float* __restrict__ out) {
    int idx = blockIdx.x * blockDim.x + threadIdx.x;
    if (idx < BB * TT) {
        int t = idx & (TT - 1);
        int b = idx >> 7;
        out[idx] = predbuf[(size_t)(t + 1) * BB + b];
    }
}

// ---- Host launch -----------------------------------------------------------

extern "C" void kernel_launch(void* const* d_in, const int* in_sizes, int n_in,
                              void* d_out, int out_size, void* d_ws, size_t ws_size,
                              hipStream_t stream) {
    const float* hidden = (const float*)d_in[0];
    const float* cell   = (const float*)d_in[1];
    const float* Wih    = (const float*)d_in[2];
    const float* Whh    = (const float*)d_in[3];
    const float* bih    = (const float*)d_in[4];
    const float* bhh    = (const float*)d_in[5];
    const float* Wout   = (const float*)d_in[6];
    const float* bout   = (const float*)d_in[7];
    float* out = (float*)d_out;

    char* ws = (char*)d_ws;
    bf16* Wr0 = (bf16*)ws;       ws += (size_t)4 * HH * HH * 2;   // 8 MB
    bf16* Wr1 = (bf16*)ws;       ws += (size_t)4 * HH * HH * 2;   // 8 MB
    bf16* hb0 = (bf16*)ws;       ws += (size_t)BB * HH * 2;       // 8 MB
    bf16* hb1 = (bf16*)ws;       ws += (size_t)BB * HH * 2;       // 8 MB
    bf16* cbuf = (bf16*)ws;      ws += (size_t)BB * HH * 2;       // 8 MB
    float* bias0 = (float*)ws;   ws += (size_t)4 * HH * 4;        // 16 KB
    float* bias1 = (float*)ws;   ws += (size_t)4 * HH * 4;        // 16 KB
    float* predbuf = (float*)ws; ws += (size_t)(TT + 1) * BB * 4; // 2.1 MB

    prep_weights<<<(4 * HH * HH + 255) / 256, 256, 0, stream>>>(
        Whh, bih, bhh, Wih, Wout, bout, Wr0, Wr1, bias0, bias1);
    prep_h<<<(BB * HH + 255) / 256, 256, 0, stream>>>(hidden, hb0);
    prep_c<<<(BB * HH + 255) / 256, 256, 0, stream>>>(cell, cbuf);
    prep_pred<<<((TT + 1) * BB + 255) / 256, 256, 0, stream>>>(predbuf, bout);

    bf16* hb[2] = {hb0, hb1};
    for (int t = 0; t < TT; t++) {
        const bf16* hr = hb[t & 1];
        bf16* hw = hb[(t + 1) & 1];
        const bf16* Wr   = (t == 0) ? Wr0 : Wr1;
        const float* bsp = (t == 0) ? bias0 : bias1;
        lstm_step<<<256, 512, 0, stream>>>(
            hr, hw, cbuf, Wr, bsp, Wout, predbuf + (size_t)(t + 1) * BB);
    }

    write_out<<<(BB * TT + 255) / 256, 256, 0, stream>>>(predbuf, out);
}